// Round 6
// baseline (308.622 us; speedup 1.0000x reference)
//
#include <hip/hip_runtime.h>

#define DIM 768
#define NEG_SLOPE 0.2f

typedef unsigned short ushort_t;
typedef short short8 __attribute__((ext_vector_type(8)));
typedef float floatx4 __attribute__((ext_vector_type(4)));

__device__ __forceinline__ ushort_t f32_to_bf16(float f) {
  unsigned int b = __float_as_uint(f);
  b += 0x7FFFu + ((b >> 16) & 1u);   // RNE
  return (ushort_t)(b >> 16);
}
__device__ __forceinline__ float bf16_to_f32(ushort_t u) {
  return __uint_as_float(((unsigned int)u) << 16);
}
__device__ __forceinline__ float bf16lo(unsigned int u) {
  return __uint_as_float(u << 16);
}
__device__ __forceinline__ float bf16hi(unsigned int u) {
  return __uint_as_float(u & 0xFFFF0000u);
}
__device__ __forceinline__ unsigned int pack_bf16x2(float lo, float hi) {
  return ((unsigned int)f32_to_bf16(lo)) | (((unsigned int)f32_to_bf16(hi)) << 16);
}

// async global->LDS, 16B per lane. LDS dest = wave-uniform base + lane*16.
__device__ __forceinline__ void gl2lds16(const ushort_t* g, ushort_t* l) {
  __builtin_amdgcn_global_load_lds(
      (const __attribute__((address_space(1))) void*)g,
      (__attribute__((address_space(3))) void*)l, 16, 0, 0);
}

// ------- fused prep: W transposes (LDS-tiled, coalesced) + x->bf16 + zero ---------
// blocks 0..287: 64x64 transpose tiles (2 matrices x 144). blocks 288+: cast/zero.
__global__ __launch_bounds__(256)
void prep_kernel(const float* __restrict__ x, ushort_t* __restrict__ xb, int n4,
                 const float* __restrict__ W1, ushort_t* __restrict__ wT1,
                 const float* __restrict__ W2, ushort_t* __restrict__ wT2,
                 int* __restrict__ zbase, int nz4) {
  __shared__ ushort_t tile[64][65];
  int b = blockIdx.x;
  int t = threadIdx.x;
  if (b < 288) {
    int mat = b / 144;
    int ti = b - mat * 144;
    int tr = (ti / 12) * 64;   // k-base (row of W)
    int tc = (ti % 12) * 64;   // n-base (col of W)
    const float* W = mat ? W2 : W1;
    ushort_t* wT = mat ? wT2 : wT1;
    int lr = t >> 4, lc4 = (t & 15) * 4;
#pragma unroll
    for (int p = 0; p < 4; ++p) {
      int row = lr + p * 16;
      float4 v = *(const float4*)(W + (size_t)(tr + row) * DIM + tc + lc4);
      tile[row][lc4 + 0] = f32_to_bf16(v.x);
      tile[row][lc4 + 1] = f32_to_bf16(v.y);
      tile[row][lc4 + 2] = f32_to_bf16(v.z);
      tile[row][lc4 + 3] = f32_to_bf16(v.w);
    }
    __syncthreads();
    int n = t & 63, kb = (t >> 6) * 16;
    ushort_t tmp[16];
#pragma unroll
    for (int i = 0; i < 16; ++i) tmp[i] = tile[kb + i][n];
    ushort_t* dst = wT + (size_t)(tc + n) * DIM + tr + kb;
    *(uint4*)(dst) = *(const uint4*)(&tmp[0]);
    *(uint4*)(dst + 8) = *(const uint4*)(&tmp[8]);
  } else {
    int i = (b - 288) * 256 + t;
    if (i < n4) {
      float4 v = ((const float4*)x)[i];
      ushort4 o;
      o.x = f32_to_bf16(v.x); o.y = f32_to_bf16(v.y);
      o.z = f32_to_bf16(v.z); o.w = f32_to_bf16(v.w);
      ((ushort4*)xb)[i] = o;
    }
    if (i < nz4) {
      ((uint4*)zbase)[i] = make_uint4(0, 0, 0, 0);
    }
  }
}

// ---------------- CSR build (by destination, self-loops appended) ----------------
__global__ void hist_kernel(const int* __restrict__ ei, int* __restrict__ deg,
                            int E, int Etot) {
  int e = blockIdx.x * 256 + threadIdx.x;
  if (e >= Etot) return;
  int d = (e < E) ? ei[E + e] : (e - E);
  atomicAdd(&deg[d], 1);
}

__global__ __launch_bounds__(1024)
void scan_kernel(const int* __restrict__ deg, int* __restrict__ rowstart,
                 int* __restrict__ cursor, int n, int etot) {
  __shared__ int sdeg[10240];
  __shared__ int part[1024];
  int tid = threadIdx.x;
  for (int i = tid; i < n; i += 1024) sdeg[i] = deg[i];
  __syncthreads();
  int chunk = ((n + 1023) / 1024) | 1;   // 11: odd stride, 2-way bank alias max
  int lo = min(tid * chunk, n);
  int hi = min(lo + chunk, n);
  int s = 0;
  for (int i = lo; i < hi; ++i) s += sdeg[i];
  part[tid] = s;
  __syncthreads();
  for (int off = 1; off < 1024; off <<= 1) {
    int v = part[tid];
    int add = (tid >= off) ? part[tid - off] : 0;
    __syncthreads();
    part[tid] = v + add;
    __syncthreads();
  }
  int run = (tid == 0) ? 0 : part[tid - 1];
  for (int i = lo; i < hi; ++i) {
    int d = sdeg[i];
    sdeg[i] = run;
    run += d;
  }
  __syncthreads();
  for (int i = tid; i < n; i += 1024) {
    int v = sdeg[i];
    rowstart[i] = v;
    cursor[i] = v;
  }
  if (tid == 0) rowstart[n] = etot;
}

__global__ void fill_kernel(const int* __restrict__ ei, int* __restrict__ cursor,
                            int* __restrict__ col, int E, int Etot) {
  int e = blockIdx.x * 256 + threadIdx.x;
  if (e >= Etot) return;
  int s, d;
  if (e < E) { s = ei[e]; d = ei[E + e]; }
  else       { s = e - E; d = e - E; }
  int pos = atomicAdd(&cursor[d], 1);
  col[pos] = s;
}

// ---------------- bf16 MFMA GEMM, 256x128 tile, 512 threads, BK=64 ----------------
// Block swizzle: blockIdx = g*48 + n*8 + (m&7) -> XCD = m&7, so all 6 N-blocks of
// one M-row run on the same XCD and share the 393 KB A-tile in its L2.
__global__ __launch_bounds__(512)
void gemm_kernel(const ushort_t* __restrict__ A, const ushort_t* __restrict__ Bt,
                 const float* __restrict__ att_s, const float* __restrict__ att_d,
                 float* __restrict__ a_s, float* __restrict__ a_d,
                 ushort_t* __restrict__ Hb, int M) {
  const int K = DIM;
  __shared__ __align__(16) ushort_t As[256 * 64];   // 32 KB
  __shared__ __align__(16) ushort_t Bs[128 * 64];   // 16 KB
  int tid = threadIdx.x;
  int b = blockIdx.x;
  int g = b / 48, r = b - g * 48;
  int nblk = r >> 3, mr = r & 7;
  int m0 = (g * 8 + mr) * 256, n0 = nblk * 128;
  int wave = tid >> 6, lane = tid & 63;
  int wm = (wave >> 1) * 64, wn = (wave & 1) * 64;  // 4(M) x 2(N) waves
  int quad = lane >> 4, l16 = lane & 15;

  floatx4 acc[4][4];
  const floatx4 fzero = {0.f, 0.f, 0.f, 0.f};
#pragma unroll
  for (int i = 0; i < 4; ++i)
#pragma unroll
    for (int j = 0; j < 4; ++j) acc[i][j] = fzero;

  // staging: per wave-call 1 KB = 8 rows x 128 B; lane = (lr<<3)|lc
  int lr = lane >> 3, lc = lane & 7;
  const ushort_t* gA[4];
  const ushort_t* gB[2];
  ushort_t* lA[4];
  ushort_t* lB[2];
#pragma unroll
  for (int t = 0; t < 4; ++t) {
    int rr = (wave * 4 + t) * 8 + lr;                // 0..255
    int gg = lc ^ (rr & 7);
    gA[t] = A + (size_t)min(m0 + rr, M - 1) * K + gg * 8;
    lA[t] = As + (wave * 4 + t) * 8 * 64;
  }
#pragma unroll
  for (int t = 0; t < 2; ++t) {
    int rr = (wave * 2 + t) * 8 + lr;                // 0..127
    int gg = lc ^ (rr & 7);
    gB[t] = Bt + (size_t)(n0 + rr) * K + gg * 8;
    lB[t] = Bs + (wave * 2 + t) * 8 * 64;
  }

  for (int k0 = 0; k0 < K; k0 += 64) {
#pragma unroll
    for (int t = 0; t < 4; ++t) gl2lds16(gA[t] + k0, lA[t]);
#pragma unroll
    for (int t = 0; t < 2; ++t) gl2lds16(gB[t] + k0, lB[t]);
    __syncthreads();

#pragma unroll
    for (int h = 0; h < 2; ++h) {
      short8 af[4], bfr[4];
#pragma unroll
      for (int i = 0; i < 4; ++i) {
        int ra = wm + i * 16 + l16;
        af[i] = *(const short8*)(As + ra * 64 + ((((h << 2) | quad)) ^ (ra & 7)) * 8);
        int rb = wn + i * 16 + l16;
        bfr[i] = *(const short8*)(Bs + rb * 64 + ((((h << 2) | quad)) ^ (rb & 7)) * 8);
      }
#pragma unroll
      for (int i = 0; i < 4; ++i)
#pragma unroll
        for (int j = 0; j < 4; ++j)
          acc[i][j] = __builtin_amdgcn_mfma_f32_16x16x32_bf16(af[i], bfr[j], acc[i][j], 0, 0, 0);
    }
    __syncthreads();
  }

  float avs[4], avd[4];
#pragma unroll
  for (int j = 0; j < 4; ++j) {
    int c = n0 + wn + j * 16 + l16;
    avs[j] = att_s[c];
    avd[j] = att_d[c];
  }

#pragma unroll
  for (int i = 0; i < 4; ++i) {
#pragma unroll
    for (int r2 = 0; r2 < 4; ++r2) {
      int row = m0 + wm + i * 16 + quad * 4 + r2;
      bool valid = row < M;
      float pvs = 0.f, pvd = 0.f;
#pragma unroll
      for (int j = 0; j < 4; ++j) {
        float v = acc[i][j][r2];
        if (valid) Hb[(size_t)row * DIM + n0 + wn + j * 16 + l16] = f32_to_bf16(v);
        pvs = fmaf(v, avs[j], pvs);
        pvd = fmaf(v, avd[j], pvd);
      }
#pragma unroll
      for (int off = 1; off < 16; off <<= 1) {
        pvs += __shfl_xor(pvs, off, 64);
        pvd += __shfl_xor(pvd, off, 64);
      }
      if (valid && l16 == 0) {
        atomicAdd(a_s + row, pvs);
        atomicAdd(a_d + row, pvd);
      }
    }
  }
}

// ---------------- XCD-slab segment softmax + gather-sum (bf16 h) ----------------
// slab = blockIdx&7 -> XCD-pinned: each XCD's 96-col slab of h (1.9 MB) stays
// resident in its private L2, so the random row gather is L2-served.
// Wave per (node, slab); lanes 0..47 own col-pairs, all 64 lanes do softmax/alpha.
__global__ __launch_bounds__(256)
void aggregate_kernel(const ushort_t* __restrict__ h, const float* __restrict__ a_s,
                      const float* __restrict__ a_d, const int* __restrict__ rowstart,
                      const int* __restrict__ col, const float* __restrict__ bias,
                      float* __restrict__ out_f32, ushort_t* __restrict__ out_bf16,
                      int relu_mode, int N) {
  int slab = blockIdx.x & 7;
  int grp = blockIdx.x >> 3;
  int wave = threadIdx.x >> 6, lane = threadIdx.x & 63;
  int node = grp * 4 + wave;
  if (node >= N) return;
  int start = rowstart[node], end = rowstart[node + 1];
  float ad = a_d[node];

  float vmax = -3.4e38f;
  for (int e = start + lane; e < end; e += 64) {
    float v = a_s[col[e]] + ad;
    v = (v > 0.f) ? v : NEG_SLOPE * v;
    vmax = fmaxf(vmax, v);
  }
#pragma unroll
  for (int off = 32; off > 0; off >>= 1) vmax = fmaxf(vmax, __shfl_xor(vmax, off, 64));

  float ssum = 0.f;
  for (int e = start + lane; e < end; e += 64) {
    float v = a_s[col[e]] + ad;
    v = (v > 0.f) ? v : NEG_SLOPE * v;
    ssum += __expf(v - vmax);
  }
#pragma unroll
  for (int off = 32; off > 0; off >>= 1) ssum += __shfl_xor(ssum, off, 64);
  float inv = 1.f / ssum;

  float acc0 = 0.f, acc1 = 0.f;
  const ushort_t* hs = h + slab * 96;
  bool active = lane < 48;

  for (int base = start; base < end; base += 64) {
    int e = base + lane;
    float al = 0.f;
    int sc = 0;
    if (e < end) {
      sc = col[e];
      float v = a_s[sc] + ad;
      v = (v > 0.f) ? v : NEG_SLOPE * v;
      al = __expf(v - vmax) * inv;
    }
    int cnt = min(64, end - base);
    for (int j = 0; j < cnt; ++j) {
      float w = __shfl(al, j, 64);
      int s = __shfl(sc, j, 64);
      if (active) {
        unsigned int u = *(const unsigned int*)(hs + (size_t)s * DIM + lane * 2);
        acc0 = fmaf(w, bf16lo(u), acc0);
        acc1 = fmaf(w, bf16hi(u), acc1);
      }
    }
  }

  if (active) {
    int c = slab * 96 + lane * 2;
    float2 bv = *(const float2*)(bias + c);
    float o0 = acc0 + bv.x;
    float o1 = acc1 + bv.y;
    if (relu_mode) {
      o0 = fmaxf(o0, 0.f);
      o1 = fmaxf(o1, 0.f);
      *(unsigned int*)(out_bf16 + (size_t)node * DIM + c) = pack_bf16x2(o0, o1);
    } else {
      *(float2*)(out_f32 + (size_t)node * DIM + c) = make_float2(o0, o1);
    }
  }
}

extern "C" void kernel_launch(void* const* d_in, const int* in_sizes, int n_in,
                              void* d_out, int out_size, void* d_ws, size_t ws_size,
                              hipStream_t stream) {
  const float* x   = (const float*)d_in[0];
  const int*   ei  = (const int*)d_in[1];
  const float* W1  = (const float*)d_in[2];
  const float* as1 = (const float*)d_in[3];
  const float* ad1 = (const float*)d_in[4];
  const float* b1  = (const float*)d_in[5];
  const float* W2  = (const float*)d_in[6];
  const float* as2 = (const float*)d_in[7];
  const float* ad2 = (const float*)d_in[8];
  const float* b2  = (const float*)d_in[9];

  const int N = in_sizes[0] / DIM;   // 10000
  const int E = in_sizes[1] / 2;     // 100000
  const int Etot = E + N;

  char* p = (char*)d_ws;
  auto alloc = [&](size_t bytes) {
    char* q = p;
    p += (bytes + 255) & ~(size_t)255;
    return q;
  };
  ushort_t* Hb     = (ushort_t*)alloc((size_t)N * DIM * 2);
  ushort_t* xb     = (ushort_t*)alloc((size_t)N * DIM * 2);
  ushort_t* wT1    = (ushort_t*)alloc((size_t)DIM * DIM * 2);
  ushort_t* wT2    = (ushort_t*)alloc((size_t)DIM * DIM * 2);
  // contiguous zeroed region: deg | a_s1 | a_d1 | a_s2 | a_d2  (zeroed in prep)
  int*      zbase  = (int*)alloc((size_t)5 * N * 4 + 16);
  int*      deg    = zbase;
  float*    a_s1   = (float*)(zbase + N);
  float*    a_d1   = (float*)(zbase + 2 * N);
  float*    a_s2   = (float*)(zbase + 3 * N);
  float*    a_d2   = (float*)(zbase + 4 * N);
  int*      rowst  = (int*)alloc((size_t)(N + 1) * 4);
  int*      cursor = (int*)alloc((size_t)N * 4);
  int*      col    = (int*)alloc((size_t)Etot * 4);

  int n4 = N * DIM / 4;
  int nz4 = (5 * N + 3) / 4;
  int prep_blocks = 288 + (n4 + 255) / 256;
  prep_kernel<<<prep_blocks, 256, 0, stream>>>(x, xb, n4, W1, wT1, W2, wT2,
                                               zbase, nz4);
  hist_kernel<<<(Etot + 255) / 256, 256, 0, stream>>>(ei, deg, E, Etot);
  scan_kernel<<<1, 1024, 0, stream>>>(deg, rowst, cursor, N, Etot);
  fill_kernel<<<(Etot + 255) / 256, 256, 0, stream>>>(ei, cursor, col, E, Etot);

  int gemm_blocks = ((N + 255) / 256) * 6 * 8 / 8;  // 40 m-blocks x 6 n-blocks = 240
  int agg_blocks = ((N + 3) / 4) * 8;               // 2500 groups x 8 slabs

  // Layer 1
  gemm_kernel<<<gemm_blocks, 512, 0, stream>>>(xb, wT1, as1, ad1, a_s1, a_d1, Hb, N);
  aggregate_kernel<<<agg_blocks, 256, 0, stream>>>(Hb, a_s1, a_d1, rowst, col, b1,
                                                   nullptr, xb, 1, N);
  // Layer 2
  gemm_kernel<<<gemm_blocks, 512, 0, stream>>>(xb, wT2, as2, ad2, a_s2, a_d2, Hb, N);
  aggregate_kernel<<<agg_blocks, 256, 0, stream>>>(Hb, a_s2, a_d2, rowst, col, b2,
                                                   (float*)d_out, nullptr, 0, N);
}

// Round 7
// 231.916 us; speedup vs baseline: 1.3307x; 1.3307x over previous
//
#include <hip/hip_runtime.h>

#define DIM 768
#define NEG_SLOPE 0.2f

typedef unsigned short ushort_t;
typedef short short8 __attribute__((ext_vector_type(8)));
typedef float floatx4 __attribute__((ext_vector_type(4)));

__device__ __forceinline__ ushort_t f32_to_bf16(float f) {
  unsigned int b = __float_as_uint(f);
  b += 0x7FFFu + ((b >> 16) & 1u);   // RNE
  return (ushort_t)(b >> 16);
}
__device__ __forceinline__ float bf16_to_f32(ushort_t u) {
  return __uint_as_float(((unsigned int)u) << 16);
}
__device__ __forceinline__ float bf16lo(unsigned int u) {
  return __uint_as_float(u << 16);
}
__device__ __forceinline__ float bf16hi(unsigned int u) {
  return __uint_as_float(u & 0xFFFF0000u);
}
__device__ __forceinline__ unsigned int pack_bf16x2(float lo, float hi) {
  return ((unsigned int)f32_to_bf16(lo)) | (((unsigned int)f32_to_bf16(hi)) << 16);
}

// async global->LDS, 16B per lane. LDS dest = wave-uniform base + lane*16.
__device__ __forceinline__ void gl2lds16(const ushort_t* g, ushort_t* l) {
  __builtin_amdgcn_global_load_lds(
      (const __attribute__((address_space(1))) void*)g,
      (__attribute__((address_space(3))) void*)l, 16, 0, 0);
}

// ------- fused prep: W transposes (LDS-tiled, coalesced) + x->bf16 + zero ---------
__global__ __launch_bounds__(256)
void prep_kernel(const float* __restrict__ x, ushort_t* __restrict__ xb, int n4,
                 const float* __restrict__ W1, ushort_t* __restrict__ wT1,
                 const float* __restrict__ W2, ushort_t* __restrict__ wT2,
                 int* __restrict__ zbase, int nz4) {
  __shared__ ushort_t tile[64][65];
  int b = blockIdx.x;
  int t = threadIdx.x;
  if (b < 288) {
    int mat = b / 144;
    int ti = b - mat * 144;
    int tr = (ti / 12) * 64;   // k-base (row of W)
    int tc = (ti % 12) * 64;   // n-base (col of W)
    const float* W = mat ? W2 : W1;
    ushort_t* wT = mat ? wT2 : wT1;
    int lr = t >> 4, lc4 = (t & 15) * 4;
#pragma unroll
    for (int p = 0; p < 4; ++p) {
      int row = lr + p * 16;
      float4 v = *(const float4*)(W + (size_t)(tr + row) * DIM + tc + lc4);
      tile[row][lc4 + 0] = f32_to_bf16(v.x);
      tile[row][lc4 + 1] = f32_to_bf16(v.y);
      tile[row][lc4 + 2] = f32_to_bf16(v.z);
      tile[row][lc4 + 3] = f32_to_bf16(v.w);
    }
    __syncthreads();
    int n = t & 63, kb = (t >> 6) * 16;
    ushort_t tmp[16];
#pragma unroll
    for (int i = 0; i < 16; ++i) tmp[i] = tile[kb + i][n];
    ushort_t* dst = wT + (size_t)(tc + n) * DIM + tr + kb;
    *(uint4*)(dst) = *(const uint4*)(&tmp[0]);
    *(uint4*)(dst + 8) = *(const uint4*)(&tmp[8]);
  } else {
    int i = (b - 288) * 256 + t;
    if (i < n4) {
      float4 v = ((const float4*)x)[i];
      ushort4 o;
      o.x = f32_to_bf16(v.x); o.y = f32_to_bf16(v.y);
      o.z = f32_to_bf16(v.z); o.w = f32_to_bf16(v.w);
      ((ushort4*)xb)[i] = o;
    }
    if (i < nz4) {
      ((uint4*)zbase)[i] = make_uint4(0, 0, 0, 0);
    }
  }
}

// ---------------- CSR build (by destination, self-loops appended) ----------------
__global__ void hist_kernel(const int* __restrict__ ei, int* __restrict__ deg,
                            int E, int Etot) {
  int e = blockIdx.x * 256 + threadIdx.x;
  if (e >= Etot) return;
  int d = (e < E) ? ei[E + e] : (e - E);
  atomicAdd(&deg[d], 1);
}

__global__ __launch_bounds__(1024)
void scan_kernel(const int* __restrict__ deg, int* __restrict__ rowstart,
                 int* __restrict__ cursor, int n, int etot) {
  __shared__ int sdeg[10240];
  __shared__ int part[1024];
  int tid = threadIdx.x;
  for (int i = tid; i < n; i += 1024) sdeg[i] = deg[i];
  __syncthreads();
  int chunk = ((n + 1023) / 1024) | 1;
  int lo = min(tid * chunk, n);
  int hi = min(lo + chunk, n);
  int s = 0;
  for (int i = lo; i < hi; ++i) s += sdeg[i];
  part[tid] = s;
  __syncthreads();
  for (int off = 1; off < 1024; off <<= 1) {
    int v = part[tid];
    int add = (tid >= off) ? part[tid - off] : 0;
    __syncthreads();
    part[tid] = v + add;
    __syncthreads();
  }
  int run = (tid == 0) ? 0 : part[tid - 1];
  for (int i = lo; i < hi; ++i) {
    int d = sdeg[i];
    sdeg[i] = run;
    run += d;
  }
  __syncthreads();
  for (int i = tid; i < n; i += 1024) {
    int v = sdeg[i];
    rowstart[i] = v;
    cursor[i] = v;
  }
  if (tid == 0) rowstart[n] = etot;
}

__global__ void fill_kernel(const int* __restrict__ ei, int* __restrict__ cursor,
                            int* __restrict__ col, int E, int Etot) {
  int e = blockIdx.x * 256 + threadIdx.x;
  if (e >= Etot) return;
  int s, d;
  if (e < E) { s = ei[e]; d = ei[E + e]; }
  else       { s = e - E; d = e - E; }
  int pos = atomicAdd(&cursor[d], 1);
  col[pos] = s;
}

// ---------------- bf16 MFMA GEMM, 64x128 tile, 256 threads, BK=64 -----------------
// Grid 8*MBLK*6: XCD x = blockIdx&7 owns contiguous m-strip (MBLK m-blocks =
// ~1280 rows, 2 MB) -> A re-reads are XCD-L2 hits; B (1.2 MB) L2-resident.
// ~4-6 blocks/CU co-resident to hide the per-iter barrier drain.
// LDS rows 64 elems, chunk-of-8 XOR swizzle (g ^ (row&7)): b128 frag reads at
// 2-way bank alias (free). Writes Hb (bf16) + fused a_s/a_d partials.
__global__ __launch_bounds__(256)
void gemm_kernel(const ushort_t* __restrict__ A, const ushort_t* __restrict__ Bt,
                 const float* __restrict__ att_s, const float* __restrict__ att_d,
                 float* __restrict__ a_s, float* __restrict__ a_d,
                 ushort_t* __restrict__ Hb, int M, int MBLK) {
  const int K = DIM;
  __shared__ __align__(16) ushort_t As[64 * 64];    // 8 KB
  __shared__ __align__(16) ushort_t Bs[128 * 64];   // 16 KB
  int b = blockIdx.x;
  int x = b & 7, sidx = b >> 3;
  int m_local = sidx / 6, nblk = sidx - m_local * 6;
  int mblk = x * MBLK + m_local;
  if (mblk * 64 >= M) return;          // uniform per block: safe early-out
  int m0 = mblk * 64, n0 = nblk * 128;
  int tid = threadIdx.x;
  int wave = tid >> 6, lane = tid & 63;
  int quad = lane >> 4, l16 = lane & 15;
  int wn = wave * 32;                  // wave covers cols [wn, wn+32)

  floatx4 acc[4][2];
  const floatx4 fzero = {0.f, 0.f, 0.f, 0.f};
#pragma unroll
  for (int i = 0; i < 4; ++i)
#pragma unroll
    for (int j = 0; j < 2; ++j) acc[i][j] = fzero;

  int lr = lane >> 3, lc = lane & 7;
  const ushort_t* gA[2];
  const ushort_t* gB[4];
  ushort_t* lA[2];
  ushort_t* lB[4];
#pragma unroll
  for (int t = 0; t < 2; ++t) {
    int r = t * 32 + wave * 8 + lr;                 // 0..63
    int g = lc ^ (r & 7);
    gA[t] = A + (size_t)min(m0 + r, M - 1) * K + g * 8;
    lA[t] = As + (t * 32 + wave * 8) * 64;
  }
#pragma unroll
  for (int t = 0; t < 4; ++t) {
    int r = t * 32 + wave * 8 + lr;                 // 0..127
    int g = lc ^ (r & 7);
    gB[t] = Bt + (size_t)(n0 + r) * K + g * 8;
    lB[t] = Bs + (t * 32 + wave * 8) * 64;
  }

  for (int k0 = 0; k0 < K; k0 += 64) {
#pragma unroll
    for (int t = 0; t < 2; ++t) gl2lds16(gA[t] + k0, lA[t]);
#pragma unroll
    for (int t = 0; t < 4; ++t) gl2lds16(gB[t] + k0, lB[t]);
    __syncthreads();

#pragma unroll
    for (int h = 0; h < 2; ++h) {
      short8 af[4], bfr[2];
#pragma unroll
      for (int i = 0; i < 4; ++i) {
        int ra = i * 16 + l16;
        af[i] = *(const short8*)(As + ra * 64 + ((((h << 2) | quad)) ^ (ra & 7)) * 8);
      }
#pragma unroll
      for (int j = 0; j < 2; ++j) {
        int rb = wn + j * 16 + l16;
        bfr[j] = *(const short8*)(Bs + rb * 64 + ((((h << 2) | quad)) ^ (rb & 7)) * 8);
      }
#pragma unroll
      for (int i = 0; i < 4; ++i)
#pragma unroll
        for (int j = 0; j < 2; ++j)
          acc[i][j] = __builtin_amdgcn_mfma_f32_16x16x32_bf16(af[i], bfr[j], acc[i][j], 0, 0, 0);
    }
    __syncthreads();
  }

  float avs[2], avd[2];
#pragma unroll
  for (int j = 0; j < 2; ++j) {
    int c = n0 + wn + j * 16 + l16;
    avs[j] = att_s[c];
    avd[j] = att_d[c];
  }

#pragma unroll
  for (int i = 0; i < 4; ++i) {
#pragma unroll
    for (int r2 = 0; r2 < 4; ++r2) {
      int row = m0 + i * 16 + quad * 4 + r2;
      bool valid = row < M;
      float pvs = 0.f, pvd = 0.f;
#pragma unroll
      for (int j = 0; j < 2; ++j) {
        float v = acc[i][j][r2];
        if (valid) Hb[(size_t)row * DIM + n0 + wn + j * 16 + l16] = f32_to_bf16(v);
        pvs = fmaf(v, avs[j], pvs);
        pvd = fmaf(v, avd[j], pvd);
      }
#pragma unroll
      for (int off = 1; off < 16; off <<= 1) {
        pvs += __shfl_xor(pvs, off, 64);
        pvd += __shfl_xor(pvd, off, 64);
      }
      if (valid && l16 == 0) {
        atomicAdd(a_s + row, pvs);
        atomicAdd(a_d + row, pvd);
      }
    }
  }
}

// ---------------- wave-per-node segment softmax + gather-sum (bf16 h) ----------------
// Lane owns cols [lane*8,+8) + [512+lane*4,+4). Gather loop software-pipelined
// 2-deep: next edge's row loads issued before current edge's FMAs.
__global__ __launch_bounds__(256)
void aggregate_kernel(const ushort_t* __restrict__ h, const float* __restrict__ a_s,
                      const float* __restrict__ a_d, const int* __restrict__ rowstart,
                      const int* __restrict__ col, const float* __restrict__ bias,
                      float* __restrict__ out_f32, ushort_t* __restrict__ out_bf16,
                      int relu_mode, int N) {
  int wave = threadIdx.x >> 6, lane = threadIdx.x & 63;
  int node = blockIdx.x * 4 + wave;
  if (node >= N) return;
  int start = rowstart[node], end = rowstart[node + 1];
  float ad = a_d[node];

  float vmax = -3.4e38f;
  for (int e = start + lane; e < end; e += 64) {
    float v = a_s[col[e]] + ad;
    v = (v > 0.f) ? v : NEG_SLOPE * v;
    vmax = fmaxf(vmax, v);
  }
#pragma unroll
  for (int off = 32; off > 0; off >>= 1) vmax = fmaxf(vmax, __shfl_xor(vmax, off, 64));

  float ssum = 0.f;
  for (int e = start + lane; e < end; e += 64) {
    float v = a_s[col[e]] + ad;
    v = (v > 0.f) ? v : NEG_SLOPE * v;
    ssum += __expf(v - vmax);
  }
#pragma unroll
  for (int off = 32; off > 0; off >>= 1) ssum += __shfl_xor(ssum, off, 64);
  float inv = 1.f / ssum;

  float acc8[8];
  float acc4[4];
#pragma unroll
  for (int k = 0; k < 8; ++k) acc8[k] = 0.f;
#pragma unroll
  for (int k = 0; k < 4; ++k) acc4[k] = 0.f;

  for (int base = start; base < end; base += 64) {
    int e = base + lane;
    float al = 0.f;
    int sc = 0;
    if (e < end) {
      sc = col[e];
      float v = a_s[sc] + ad;
      v = (v > 0.f) ? v : NEG_SLOPE * v;
      al = __expf(v - vmax) * inv;
    }
    int cnt = min(64, end - base);
    // software-pipelined gather: load j+1 while accumulating j
    float w = __shfl(al, 0, 64);
    int s = __shfl(sc, 0, 64);
    const ushort_t* hr = h + (size_t)s * DIM;
    uint4 u = *(const uint4*)(hr + lane * 8);
    ushort4 t4 = *(const ushort4*)(hr + 512 + lane * 4);
    for (int j = 0; j < cnt; ++j) {
      float wn_ = 0.f;
      uint4 un;
      ushort4 tn;
      if (j + 1 < cnt) {
        wn_ = __shfl(al, j + 1, 64);
        int sn = __shfl(sc, j + 1, 64);
        const ushort_t* hrn = h + (size_t)sn * DIM;
        un = *(const uint4*)(hrn + lane * 8);
        tn = *(const ushort4*)(hrn + 512 + lane * 4);
      }
      acc8[0] = fmaf(w, bf16lo(u.x), acc8[0]);
      acc8[1] = fmaf(w, bf16hi(u.x), acc8[1]);
      acc8[2] = fmaf(w, bf16lo(u.y), acc8[2]);
      acc8[3] = fmaf(w, bf16hi(u.y), acc8[3]);
      acc8[4] = fmaf(w, bf16lo(u.z), acc8[4]);
      acc8[5] = fmaf(w, bf16hi(u.z), acc8[5]);
      acc8[6] = fmaf(w, bf16lo(u.w), acc8[6]);
      acc8[7] = fmaf(w, bf16hi(u.w), acc8[7]);
      acc4[0] = fmaf(w, bf16_to_f32(t4.x), acc4[0]);
      acc4[1] = fmaf(w, bf16_to_f32(t4.y), acc4[1]);
      acc4[2] = fmaf(w, bf16_to_f32(t4.z), acc4[2]);
      acc4[3] = fmaf(w, bf16_to_f32(t4.w), acc4[3]);
      if (j + 1 < cnt) { w = wn_; u = un; t4 = tn; }
    }
  }

  size_t ob = (size_t)node * DIM;
  int c8 = lane * 8, c4 = 512 + lane * 4;
  float4 b0 = *(const float4*)(bias + c8);
  float4 b1 = *(const float4*)(bias + c8 + 4);
  float4 b2 = *(const float4*)(bias + c4);
  float o[12];
  o[0] = acc8[0] + b0.x; o[1] = acc8[1] + b0.y;
  o[2] = acc8[2] + b0.z; o[3] = acc8[3] + b0.w;
  o[4] = acc8[4] + b1.x; o[5] = acc8[5] + b1.y;
  o[6] = acc8[6] + b1.z; o[7] = acc8[7] + b1.w;
  o[8] = acc4[0] + b2.x; o[9] = acc4[1] + b2.y;
  o[10] = acc4[2] + b2.z; o[11] = acc4[3] + b2.w;
  if (relu_mode) {
#pragma unroll
    for (int k = 0; k < 12; ++k) o[k] = fmaxf(o[k], 0.f);
    uint4 s0;
    s0.x = pack_bf16x2(o[0], o[1]);
    s0.y = pack_bf16x2(o[2], o[3]);
    s0.z = pack_bf16x2(o[4], o[5]);
    s0.w = pack_bf16x2(o[6], o[7]);
    *(uint4*)(out_bf16 + ob + c8) = s0;
    uint2 s1;
    s1.x = pack_bf16x2(o[8], o[9]);
    s1.y = pack_bf16x2(o[10], o[11]);
    *(uint2*)(out_bf16 + ob + c4) = s1;
  } else {
    *(float4*)(out_f32 + ob + c8) = make_float4(o[0], o[1], o[2], o[3]);
    *(float4*)(out_f32 + ob + c8 + 4) = make_float4(o[4], o[5], o[6], o[7]);
    *(float4*)(out_f32 + ob + c4) = make_float4(o[8], o[9], o[10], o[11]);
  }
}

extern "C" void kernel_launch(void* const* d_in, const int* in_sizes, int n_in,
                              void* d_out, int out_size, void* d_ws, size_t ws_size,
                              hipStream_t stream) {
  const float* x   = (const float*)d_in[0];
  const int*   ei  = (const int*)d_in[1];
  const float* W1  = (const float*)d_in[2];
  const float* as1 = (const float*)d_in[3];
  const float* ad1 = (const float*)d_in[4];
  const float* b1  = (const float*)d_in[5];
  const float* W2  = (const float*)d_in[6];
  const float* as2 = (const float*)d_in[7];
  const float* ad2 = (const float*)d_in[8];
  const float* b2  = (const float*)d_in[9];

  const int N = in_sizes[0] / DIM;   // 10000
  const int E = in_sizes[1] / 2;     // 100000
  const int Etot = E + N;

  char* p = (char*)d_ws;
  auto alloc = [&](size_t bytes) {
    char* q = p;
    p += (bytes + 255) & ~(size_t)255;
    return q;
  };
  ushort_t* Hb     = (ushort_t*)alloc((size_t)N * DIM * 2);
  ushort_t* xb     = (ushort_t*)alloc((size_t)N * DIM * 2);
  ushort_t* wT1    = (ushort_t*)alloc((size_t)DIM * DIM * 2);
  ushort_t* wT2    = (ushort_t*)alloc((size_t)DIM * DIM * 2);
  // contiguous zeroed region: deg | a_s1 | a_d1 | a_s2 | a_d2  (zeroed in prep)
  int*      zbase  = (int*)alloc((size_t)5 * N * 4 + 16);
  int*      deg    = zbase;
  float*    a_s1   = (float*)(zbase + N);
  float*    a_d1   = (float*)(zbase + 2 * N);
  float*    a_s2   = (float*)(zbase + 3 * N);
  float*    a_d2   = (float*)(zbase + 4 * N);
  int*      rowst  = (int*)alloc((size_t)(N + 1) * 4);
  int*      cursor = (int*)alloc((size_t)N * 4);
  int*      col    = (int*)alloc((size_t)Etot * 4);

  int n4 = N * DIM / 4;
  int nz4 = (5 * N + 3) / 4;
  int prep_blocks = 288 + (n4 + 255) / 256;
  prep_kernel<<<prep_blocks, 256, 0, stream>>>(x, xb, n4, W1, wT1, W2, wT2,
                                               zbase, nz4);
  hist_kernel<<<(Etot + 255) / 256, 256, 0, stream>>>(ei, deg, E, Etot);
  scan_kernel<<<1, 1024, 0, stream>>>(deg, rowst, cursor, N, Etot);
  fill_kernel<<<(Etot + 255) / 256, 256, 0, stream>>>(ei, cursor, col, E, Etot);

  int MB = (N + 63) / 64;            // 157 m-blocks
  int MBLK = (MB + 7) / 8;           // 20 m-blocks per XCD strip
  int gemm_blocks = 8 * MBLK * 6;    // 960
  int agg_blocks = (N + 3) / 4;      // 2500

  // Layer 1
  gemm_kernel<<<gemm_blocks, 256, 0, stream>>>(xb, wT1, as1, ad1, a_s1, a_d1, Hb, N, MBLK);
  aggregate_kernel<<<agg_blocks, 256, 0, stream>>>(Hb, a_s1, a_d1, rowst, col, b1,
                                                   nullptr, xb, 1, N);
  // Layer 2
  gemm_kernel<<<gemm_blocks, 256, 0, stream>>>(xb, wT2, as2, ad2, a_s2, a_d2, Hb, N, MBLK);
  aggregate_kernel<<<agg_blocks, 256, 0, stream>>>(Hb, a_s2, a_d2, rowst, col, b2,
                                                   (float*)d_out, nullptr, 0, N);
}